// Round 15
// baseline (502.225 us; speedup 1.0000x reference)
//
#include <hip/hip_runtime.h>
#include <hip/hip_bf16.h>

#define NN 50000          // nodes
#define NE 800000         // edges
#define NR 3              // relations
#define NG 500            // graphs
#define NB (NN * NR)      // (dst, rel) buckets = 150000
#define NCLS 10
#define NCMB 8192         // 8 shapes * 8 colors * 128 positions
#define CHUNK 2048        // scan elements per block
#define NBLK ((NB + CHUNK - 1) / CHUNK)   // 74

// prep1 role block ranges
#define P1_COMBO   196                        // node_combo: 50000/256
#define P1_ZCNT    586                        // zero cnt: 150000/256
#define P1_ZPOOL   502                        // zero pool+gcnt: 128500/256
#define P1_TAB     576                        // tab_gemm: 4*144
#define P1_WF      1024                       // conv_w2cat: 256*1024/256
#define P1_TOTAL   (P1_COMBO + P1_ZCNT + P1_ZPOOL + P1_TAB + P1_WF)   // 2884
// prep2 role block ranges
#define P2_CNT     3125                       // count_edges: NE/256
#define P2_COMB    (4 * NCMB)                 // comb_build
#define P2_TOTAL   (P2_CNT + P2_COMB)         // 35893

typedef __hip_bfloat16 bf16;
typedef __attribute__((ext_vector_type(8))) short short8;   // bf16x8 MFMA frag
typedef __attribute__((ext_vector_type(4))) float floatx4;  // MFMA accumulator

static __device__ __forceinline__ float b2f(bf16 x) { return __bfloat162float(x); }
static __device__ __forceinline__ bf16  f2b(float x) { return __float2bfloat16(x); }
static __device__ __forceinline__ float bs2f(short x) {
    return __bfloat162float(*reinterpret_cast<const bf16*>(&x));
}
static __device__ __forceinline__ short f2bs(float x) {
    bf16 b = __float2bfloat16(x);
    return *reinterpret_cast<const short*>(&b);
}

// ---------------- prep1: all independent prep work, role-dispatched by blockIdx
__global__ __launch_bounds__(256) void prep1(const int* __restrict__ s,
                                             const int* __restrict__ c,
                                             const int* __restrict__ p,
                                             const float* __restrict__ se,
                                             const float* __restrict__ ce,
                                             const float* __restrict__ pe,
                                             const float* __restrict__ W1,
                                             const float* __restrict__ root1,
                                             const float* __restrict__ W2,
                                             const float* __restrict__ root2,
                                             int* __restrict__ combo,
                                             unsigned* __restrict__ cnt,
                                             unsigned* __restrict__ poolz,
                                             float* __restrict__ tab,
                                             bf16* __restrict__ Wf) {
    int b = blockIdx.x, t = threadIdx.x;
    if (b < P1_COMBO) {
        int n = b * 256 + t;
        if (n < NN) combo[n] = (s[n] << 10) | (c[n] << 7) | p[n];
        return;
    }
    b -= P1_COMBO;
    if (b < P1_ZCNT) {
        int i = b * 256 + t;
        if (i < NB) cnt[i] = 0u;
        return;
    }
    b -= P1_ZCNT;
    if (b < P1_ZPOOL) {
        int i = b * 256 + t;
        if (i < NG * 256 + NG) poolz[i] = 0u;
        return;
    }
    b -= P1_ZPOOL;
    if (b < P1_TAB) {
        // tab[r][row][n]: rows 0..7 = se@Wseg0, 8..15 = ce@Wseg1, 16..143 = pe@Wseg2
        int r = b / 144, row = b % 144;
        const float* A; int segk;
        if (row < 8)       { A = se + row * 128;        segk = 0; }
        else if (row < 16) { A = ce + (row - 8) * 128;  segk = 128; }
        else               { A = pe + (row - 16) * 128; segk = 256; }
        const float* W = (r < 3) ? (W1 + (size_t)r * 384 * 256) : root1;
        float acc = 0.f;
        for (int k = 0; k < 128; ++k)
            acc += A[k] * W[(size_t)(segk + k) * 256 + t];
        tab[((size_t)r * 144 + row) * 256 + t] = acc;
        return;
    }
    b -= P1_TAB;
    {   // conv_w2cat: Wf in MFMA-fragment order (wave B-frag = contiguous 1 KB)
        int idx = b * 256 + t;
        int j     = idx & 7;
        int lane  = (idx >> 3) & 63;
        int ni    = (idx >> 9) & 3;
        int chunk = (idx >> 11) & 31;
        int colblk = idx >> 16;
        int col = colblk * 64 + ni * 16 + (lane & 15);
        int k   = chunk * 32 + (lane >> 4) * 8 + j;
        float v = (k < 768) ? W2[((size_t)(k >> 8) * 256 + (k & 255)) * 256 + col]
                            : root2[(size_t)(k - 768) * 256 + col];
        Wf[idx] = f2b(v);
    }
}

// ---------------- prep2: count_edges + comb_build
__global__ __launch_bounds__(256) void prep2(const int* __restrict__ ei,
                                             const int* __restrict__ et,
                                             int* __restrict__ cnt,
                                             const float* __restrict__ tab,
                                             const float* __restrict__ b1,
                                             bf16* __restrict__ comb) {
    int b = blockIdx.x, t = threadIdx.x;
    if (b < P2_CNT) {
        int e = b * 256 + t;
        if (e < NE) atomicAdd(&cnt[ei[NE + e] * NR + et[e]], 1);
        return;
    }
    b -= P2_CNT;
    {   // comb[r][cmb][d] = tab[r][s]+tab[r][8+c]+tab[r][16+p] (+b1 for r=3)
        int r = b >> 13, cmb = b & (NCMB - 1);
        int si = cmb >> 10, ci = (cmb >> 7) & 7, pi = cmb & 127;
        const float* tr = tab + (size_t)r * 144 * 256;
        float v = tr[si * 256 + t] + tr[(8 + ci) * 256 + t] + tr[(16 + pi) * 256 + t];
        if (r == 3) v += b1[t];
        comb[(size_t)b * 256 + t] = f2b(v);
    }
}

// ---------------- single-kernel counting-sort scan: each block computes its own
// cross-block base by summing cnt[0 .. b*2048) coalesced; last block writes off[NB].
__global__ __launch_bounds__(256) void scan_write(const int* __restrict__ cnt,
                                                  int* __restrict__ off,
                                                  int* __restrict__ cursor) {
    __shared__ int sred[256];
    __shared__ int wsum[4];
    int b = blockIdx.x, t = threadIdx.x;
    long lim = (long)b * CHUNK;
    int partial = 0;
    for (long i = t; i < lim; i += 256) partial += cnt[i];
    sred[t] = partial;
    __syncthreads();
    for (int st = 128; st; st >>= 1) { if (t < st) sred[t] += sred[t + st]; __syncthreads(); }
    int bbase = sred[0];

    int base = b * CHUNK + t * 8;
    int v[8], ts = 0;
#pragma unroll
    for (int j = 0; j < 8; ++j) { int i = base + j; v[j] = (i < NB) ? cnt[i] : 0; ts += v[j]; }
    int lane = t & 63, wv = t >> 6;
    int incl = ts;
    for (int d = 1; d < 64; d <<= 1) {
        int o = __shfl_up(incl, d, 64);
        if (lane >= d) incl += o;
    }
    if (lane == 63) wsum[wv] = incl;
    __syncthreads();
    int wbase = 0;
    for (int w = 0; w < wv; ++w) wbase += wsum[w];
    if (b == NBLK - 1 && t == 0)
        off[NB] = bbase + wsum[0] + wsum[1] + wsum[2] + wsum[3];   // == NE
    int run = bbase + wbase + incl - ts;
#pragma unroll
    for (int j = 0; j < 8; ++j) {
        int i = base + j;
        if (i < NB) { off[i] = run; cursor[i] = run; }
        run += v[j];
    }
}

// ---------------- bucket-sort edges: stores src AND combo[src]
__global__ __launch_bounds__(256) void scatter_edges(const int* __restrict__ ei,
                                                     const int* __restrict__ et,
                                                     const int* __restrict__ combo,
                                                     int* __restrict__ cursor,
                                                     int* __restrict__ eidx,
                                                     int* __restrict__ ecmb) {
    int e = blockIdx.x * 256 + threadIdx.x;
    if (e >= NE) return;
    int b = ei[NE + e] * NR + et[e];
    int pos = atomicAdd(&cursor[b], 1);
    int s = ei[e];
    eidx[pos] = s;
    ecmb[pos] = combo[s];
}

// ---------------- fused layer 1: 4 waves/block, 1 wave/dst, lane-split 8-deep gather
__global__ __launch_bounds__(256) void l1_fused(const int* __restrict__ off,
                                                const int* __restrict__ ecmb,
                                                const int* __restrict__ combo,
                                                const bf16* __restrict__ comb,
                                                bf16* __restrict__ h1) {
    int wave = threadIdx.x >> 6, lane = threadIdx.x & 63;
    int dst = blockIdx.x * 4 + wave;
    if (dst >= NN) return;
    int half = lane >> 5, li8 = (lane & 31) * 8;
    float acc[8];
    if (half == 0) {   // root slice (b1 pre-folded); only half0's acc is used
        int cmbD = combo[dst];
        short8 rv = *(const short8*)(comb + ((size_t)(3 * NCMB) + cmbD) * 256 + li8);
#pragma unroll
        for (int i = 0; i < 8; ++i) acc[i] = bs2f(rv[i]);
    } else {
#pragma unroll
        for (int i = 0; i < 8; ++i) acc[i] = 0.f;
    }
    for (int r = 0; r < NR; ++r) {
        int lo = off[dst * NR + r], hi = off[dst * NR + r + 1];
        if (hi <= lo) continue;                 // empty bucket contributes 0 (matches ref)
        const bf16* cr = comb + (size_t)r * NCMB * 256;
        float s[8] = {};
        int j = lo;
        for (; j + 8 <= hi; j += 8) {           // 4 rows/half in flight
            int c0 = ecmb[j + half],     c1 = ecmb[j + 2 + half];
            int c2 = ecmb[j + 4 + half], c3 = ecmb[j + 6 + half];
            short8 v0 = *(const short8*)(cr + (size_t)c0 * 256 + li8);
            short8 v1 = *(const short8*)(cr + (size_t)c1 * 256 + li8);
            short8 v2 = *(const short8*)(cr + (size_t)c2 * 256 + li8);
            short8 v3 = *(const short8*)(cr + (size_t)c3 * 256 + li8);
#pragma unroll
            for (int i = 0; i < 8; ++i)
                s[i] += (bs2f(v0[i]) + bs2f(v1[i])) + (bs2f(v2[i]) + bs2f(v3[i]));
        }
        for (; j + 2 <= hi; j += 2) {
            int c0 = ecmb[j + half];
            short8 v0 = *(const short8*)(cr + (size_t)c0 * 256 + li8);
#pragma unroll
            for (int i = 0; i < 8; ++i) s[i] += bs2f(v0[i]);
        }
        if (j < hi && half == 0) {              // odd remainder
            short8 v0 = *(const short8*)(cr + (size_t)ecmb[j] * 256 + li8);
#pragma unroll
            for (int i = 0; i < 8; ++i) s[i] += bs2f(v0[i]);
        }
        float inv = 1.0f / (float)(hi - lo);
#pragma unroll
        for (int i = 0; i < 8; ++i) {
            float tot = s[i] + __shfl_xor(s[i], 32);
            if (half == 0) acc[i] += tot * inv;
        }
    }
    if (half == 0) {
        short8 o;
#pragma unroll
        for (int i = 0; i < 8; ++i) o[i] = f2bs(fmaxf(acc[i], 0.f));
        *(short8*)(h1 + (size_t)dst * 256 + li8) = o;
    }
}

// ---------------- FUSED layer-2 v2: 512 threads (8 waves) per 32-row block ->
// 2 blocks/CU = 16 gathering waves/CU (2x round 14 -> 2x gather BW).
// Phase 1: 16 half-slots gather 96 bucket-means + 32 h1 tail rows into a 64 KB
// swizzled LDS A-tile [32 x 1024]. One barrier. Phase 2: 8 waves, each 16 rows x
// 64 cols (1x4 MFMA grid); wave pairs share B stripes (L1 reuse).
__global__ __launch_bounds__(512) void agg_gemm(const int* __restrict__ off,
                                                const int* __restrict__ eidx,
                                                const bf16* __restrict__ h1,
                                                const bf16* __restrict__ Wf,
                                                const float* __restrict__ bias,
                                                bf16* __restrict__ h2) {
    __shared__ short Alds[32 * 1024];       // 64 KB
    const int t = threadIdx.x;
    const int wave = t >> 6, lane = t & 63;
    const int half = lane >> 5, l32 = lane & 31;
    const int hs = wave * 2 + half;         // half-slot 0..15
    const int row0 = blockIdx.x * 32;

    // ---- phase 1a: copy h1 tail rows (k=768..1023); 2 rows per half-slot
#pragma unroll
    for (int j = 0; j < 2; ++j) {
        int lrow = hs * 2 + j;
        int dst = row0 + lrow;
        short8 v = {};
        if (dst < NN) v = *(const short8*)(h1 + (size_t)dst * 256 + l32 * 8);
        *(short8*)&Alds[lrow * 1024 + (((96 + l32) ^ (lrow & 7)) * 8)] = v;
    }
    // ---- phase 1b: 6 (dst,rel) buckets per half-slot (96 total)
    for (int i = 0; i < 6; ++i) {
        int bidx = hs * 6 + i;              // 0..95
        int lrow = bidx / 3, r = bidx % 3;
        int dst = row0 + lrow;
        float s[8] = {};
        float inv = 0.f;
        if (dst < NN) {
            int bk = dst * NR + r;
            int lo = off[bk], hi = off[bk + 1];
            if (hi > lo) {
                int j = lo;
                for (; j + 4 <= hi; j += 4) {   // 4 rows in flight per half
                    int e0 = eidx[j], e1 = eidx[j + 1], e2 = eidx[j + 2], e3 = eidx[j + 3];
                    short8 v0 = *(const short8*)(h1 + (size_t)e0 * 256 + l32 * 8);
                    short8 v1 = *(const short8*)(h1 + (size_t)e1 * 256 + l32 * 8);
                    short8 v2 = *(const short8*)(h1 + (size_t)e2 * 256 + l32 * 8);
                    short8 v3 = *(const short8*)(h1 + (size_t)e3 * 256 + l32 * 8);
#pragma unroll
                    for (int q = 0; q < 8; ++q)
                        s[q] += (bs2f(v0[q]) + bs2f(v1[q])) + (bs2f(v2[q]) + bs2f(v3[q]));
                }
                for (; j < hi; ++j) {
                    short8 v0 = *(const short8*)(h1 + (size_t)eidx[j] * 256 + l32 * 8);
#pragma unroll
                    for (int q = 0; q < 8; ++q) s[q] += bs2f(v0[q]);
                }
                inv = 1.0f / (float)(hi - lo);
            }
        }
        short8 o;
#pragma unroll
        for (int q = 0; q < 8; ++q) o[q] = f2bs(s[q] * inv);
        *(short8*)&Alds[lrow * 1024 + (((r * 32 + l32) ^ (lrow & 7)) * 8)] = o;
    }
    __syncthreads();                        // the ONLY barrier

    // ---- phase 2: wave w -> cols (w&3)*64..+64, rows (w>>2)*16..+16
    const int quad = lane >> 4, l16 = lane & 15;
    const int colblk = wave & 3, rowh = wave >> 2;
    const int arow = rowh * 16 + l16;
    const short8* bbase = (const short8*)Wf + (size_t)colblk * (32 * 4 * 64) + lane;
    auto loadB = [&](int c, short8* bf4) {
        const short8* bp = bbase + (size_t)c * 256;
#pragma unroll
        for (int ni = 0; ni < 4; ++ni) bf4[ni] = bp[ni * 64];
    };
    auto ldA = [&](int c) -> short8 {
        return *(const short8*)&Alds[arow * 1024 + ((((c << 2) + quad) ^ (arow & 7)) * 8)];
    };

    floatx4 acc[4] = {};
    short8 bE[4], bO[4];
    loadB(0, bE); loadB(1, bO);
#pragma unroll
    for (int c = 0; c < 32; c += 2) {
        {
            short8 a = ldA(c);
#pragma unroll
            for (int ni = 0; ni < 4; ++ni)
                acc[ni] = __builtin_amdgcn_mfma_f32_16x16x32_bf16(a, bE[ni], acc[ni], 0, 0, 0);
        }
        if (c + 2 < 32) loadB(c + 2, bE);
        {
            short8 a = ldA(c + 1);
#pragma unroll
            for (int ni = 0; ni < 4; ++ni)
                acc[ni] = __builtin_amdgcn_mfma_f32_16x16x32_bf16(a, bO[ni], acc[ni], 0, 0, 0);
        }
        if (c + 3 < 32) loadB(c + 3, bO);
    }

    // C/D layout: col = lane&15, row = quad*4 + reg   [m89/m91-verified]
#pragma unroll
    for (int ni = 0; ni < 4; ++ni) {
        int n = colblk * 64 + ni * 16 + l16;
        float bn = bias[n];
#pragma unroll
        for (int ii = 0; ii < 4; ++ii) {
            int gm = row0 + rowh * 16 + quad * 4 + ii;
            if (gm < NN) {
                float v = acc[ni][ii] + bn;
                h2[(size_t)gm * 256 + n] = f2b(fmaxf(v, 0.f));
            }
        }
    }
}

// ---------------- pooling via run-length reduction (batch is SORTED)
#define PN 64
__global__ __launch_bounds__(256) void pool_rle(const int* __restrict__ batch,
                                                const bf16* __restrict__ H,
                                                float* __restrict__ pool,
                                                float* __restrict__ gcnt) {
    int t = threadIdx.x;               // feature dim
    int n0 = blockIdx.x * PN;
    int nend = n0 + PN; if (nend > NN) nend = NN;
    int curg = batch[n0];
    float acc = 0.f, cnt = 0.f;
    for (int n = n0; n < nend; ++n) {
        int g = batch[n];              // wave-uniform
        if (g != curg) {
            atomicAdd(&pool[(size_t)curg * 256 + t], acc);
            if (t == 0) atomicAdd(&gcnt[curg], cnt);
            acc = 0.f; cnt = 0.f; curg = g;
        }
        acc += b2f(H[(size_t)n * 256 + t]);
        cnt += 1.f;
    }
    atomicAdd(&pool[(size_t)curg * 256 + t], acc);
    if (t == 0) atomicAdd(&gcnt[curg], cnt);
}

// ---------------- head: out[g][c] = (pool[g]/cnt[g]) @ lin_w + lin_b  (f32 out)
__global__ __launch_bounds__(256) void final_head(const float* __restrict__ pool,
                                                  const float* __restrict__ gcnt,
                                                  const float* __restrict__ lin_w,
                                                  const float* __restrict__ lin_b,
                                                  float* __restrict__ out) {
    __shared__ float sm[256];
    int g = blockIdx.x, t = threadIdx.x;
    float inv = 1.0f / fmaxf(gcnt[g], 1.0f);
    sm[t] = pool[(size_t)g * 256 + t] * inv;
    __syncthreads();
    if (t < NCLS) {
        float s = lin_b[t];
        for (int d = 0; d < 256; ++d) s += sm[d] * lin_w[d * NCLS + t];
        out[g * NCLS + t] = s;
    }
}

extern "C" void kernel_launch(void* const* d_in, const int* in_sizes, int n_in,
                              void* d_out, int out_size, void* d_ws, size_t ws_size,
                              hipStream_t stream) {
    const int*   s_idx = (const int*)d_in[0];
    const int*   c_idx = (const int*)d_in[1];
    const int*   p_idx = (const int*)d_in[2];
    const int*   ei    = (const int*)d_in[3];   // (2, NE)
    const int*   et    = (const int*)d_in[4];
    const int*   batch = (const int*)d_in[5];
    const float* se    = (const float*)d_in[6];
    const float* ce    = (const float*)d_in[7];
    const float* pe    = (const float*)d_in[8];
    const float* W1    = (const float*)d_in[9];   // (3, 384, 256)
    const float* root1 = (const float*)d_in[10];  // (384, 256)
    const float* b1    = (const float*)d_in[11];
    const float* W2    = (const float*)d_in[12];  // (3, 256, 256)
    const float* root2 = (const float*)d_in[13];  // (256, 256)
    const float* b2    = (const float*)d_in[14];
    const float* lin_w = (const float*)d_in[15];
    const float* lin_b = (const float*)d_in[16];
    float* out = (float*)d_out;

    // ---- workspace carve-up (~98 MB)
    char* w = (char*)d_ws;
    size_t o = 0;
    auto alloc = [&](size_t bytes) -> void* {
        o = (o + 15) & ~(size_t)15;
        void* ptr = w + o;
        o += bytes;
        return ptr;
    };
    bf16*  h1     = (bf16*) alloc((size_t)NN * 256 * 2);
    bf16*  h2     = (bf16*) alloc((size_t)NN * 256 * 2);
    bf16*  comb   = (bf16*) alloc((size_t)4 * NCMB * 256 * 2);
    int*   combo  = (int*)  alloc((size_t)NN * 4);
    int*   eidx   = (int*)  alloc((size_t)NE * 4);
    int*   ecmb   = (int*)  alloc((size_t)NE * 4);
    int*   cnt    = (int*)  alloc((size_t)NB * 4);
    int*   off    = (int*)  alloc((size_t)(NB + 1) * 4);
    int*   cursor = (int*)  alloc((size_t)NB * 4);
    float* tab    = (float*)alloc((size_t)4 * 144 * 256 * 4);
    bf16*  Wf     = (bf16*) alloc((size_t)256 * 1024 * 2);
    float* pool   = (float*)alloc((size_t)NG * 256 * 4);   // pool + gcnt contiguous
    float* gcnt   = (float*)alloc((size_t)NG * 4);
    (void)ws_size;

    // ---- 1. all independent prep (combo ids, zeros, layer-1 tab GEMM, Wf shuffle)
    prep1<<<P1_TOTAL, 256, 0, stream>>>(s_idx, c_idx, p_idx, se, ce, pe,
                                        W1, root1, W2, root2,
                                        combo, (unsigned*)cnt, (unsigned*)pool, tab, Wf);
    // ---- 2. edge counts + combo-table build
    prep2<<<P2_TOTAL, 256, 0, stream>>>(ei, et, cnt, tab, b1, comb);
    // ---- 3. single-kernel CSR scan (block base computed inline from cnt)
    scan_write<<<NBLK, 256, 0, stream>>>(cnt, off, cursor);
    // ---- 4. bucket-sort edges
    scatter_edges<<<(NE + 255) / 256, 256, 0, stream>>>(ei, et, combo, cursor, eidx, ecmb);
    // ---- 5. layer 1: fully fused combo-table gather
    l1_fused<<<(NN + 3) / 4, 256, 0, stream>>>(off, ecmb, combo, comb, h1);
    // ---- 6. layer 2: FUSED gather-into-LDS + MFMA GEMM, 512-thread blocks
    agg_gemm<<<(NN + 31) / 32, 512, 0, stream>>>(off, eidx, h1, Wf, b2, h2);
    // ---- 7-8. pool + head
    pool_rle<<<(NN + PN - 1) / PN, 256, 0, stream>>>(batch, h2, pool, gcnt);
    final_head<<<NG, 256, 0, stream>>>(pool, gcnt, lin_w, lin_b, out);
}

// Round 16
// 458.208 us; speedup vs baseline: 1.0961x; 1.0961x over previous
//
#include <hip/hip_runtime.h>
#include <hip/hip_bf16.h>

#define NN 50000          // nodes
#define NE 800000         // edges
#define NR 3              // relations
#define NG 500            // graphs
#define NB (NN * NR)      // (dst, rel) buckets = 150000
#define NCLS 10
#define NCMB 8192         // 8 shapes * 8 colors * 128 positions
#define CHUNK 2048        // scan elements per block
#define NBLK ((NB + CHUNK - 1) / CHUNK)   // 74

// prep1 role block ranges
#define P1_COMBO   196                        // node_combo: 50000/256
#define P1_ZCNT    586                        // zero cnt: 150000/256
#define P1_ZPOOL   502                        // zero pool+gcnt: 128500/256
#define P1_TAB     576                        // tab_gemm: 4*144
#define P1_WF      1024                       // conv_w2cat: 256*1024/256
#define P1_TOTAL   (P1_COMBO + P1_ZCNT + P1_ZPOOL + P1_TAB + P1_WF)   // 2884
// prep2 role block ranges
#define P2_CNT     3125                       // count_edges: NE/256
#define P2_COMB    (4 * NCMB)                 // comb_build
#define P2_TOTAL   (P2_CNT + P2_COMB)         // 35893

typedef __hip_bfloat16 bf16;
typedef __attribute__((ext_vector_type(8))) short short8;   // bf16x8 MFMA frag
typedef __attribute__((ext_vector_type(4))) float floatx4;  // MFMA accumulator

static __device__ __forceinline__ float b2f(bf16 x) { return __bfloat162float(x); }
static __device__ __forceinline__ bf16  f2b(float x) { return __float2bfloat16(x); }
static __device__ __forceinline__ float bs2f(short x) {
    return __bfloat162float(*reinterpret_cast<const bf16*>(&x));
}
static __device__ __forceinline__ short f2bs(float x) {
    bf16 b = __float2bfloat16(x);
    return *reinterpret_cast<const short*>(&b);
}

// ---------------- prep1: all independent prep work, role-dispatched by blockIdx
__global__ __launch_bounds__(256) void prep1(const int* __restrict__ s,
                                             const int* __restrict__ c,
                                             const int* __restrict__ p,
                                             const float* __restrict__ se,
                                             const float* __restrict__ ce,
                                             const float* __restrict__ pe,
                                             const float* __restrict__ W1,
                                             const float* __restrict__ root1,
                                             const float* __restrict__ W2,
                                             const float* __restrict__ root2,
                                             int* __restrict__ combo,
                                             unsigned* __restrict__ cnt,
                                             unsigned* __restrict__ poolz,
                                             float* __restrict__ tab,
                                             bf16* __restrict__ Wf) {
    int b = blockIdx.x, t = threadIdx.x;
    if (b < P1_COMBO) {
        int n = b * 256 + t;
        if (n < NN) combo[n] = (s[n] << 10) | (c[n] << 7) | p[n];
        return;
    }
    b -= P1_COMBO;
    if (b < P1_ZCNT) {
        int i = b * 256 + t;
        if (i < NB) cnt[i] = 0u;
        return;
    }
    b -= P1_ZCNT;
    if (b < P1_ZPOOL) {
        int i = b * 256 + t;
        if (i < NG * 256 + NG) poolz[i] = 0u;
        return;
    }
    b -= P1_ZPOOL;
    if (b < P1_TAB) {
        // tab[r][row][n]: rows 0..7 = se@Wseg0, 8..15 = ce@Wseg1, 16..143 = pe@Wseg2
        int r = b / 144, row = b % 144;
        const float* A; int segk;
        if (row < 8)       { A = se + row * 128;        segk = 0; }
        else if (row < 16) { A = ce + (row - 8) * 128;  segk = 128; }
        else               { A = pe + (row - 16) * 128; segk = 256; }
        const float* W = (r < 3) ? (W1 + (size_t)r * 384 * 256) : root1;
        float acc = 0.f;
        for (int k = 0; k < 128; ++k)
            acc += A[k] * W[(size_t)(segk + k) * 256 + t];
        tab[((size_t)r * 144 + row) * 256 + t] = acc;
        return;
    }
    b -= P1_TAB;
    {   // conv_w2cat: Wf in MFMA-fragment order (wave B-frag = contiguous 1 KB)
        int idx = b * 256 + t;
        int j     = idx & 7;
        int lane  = (idx >> 3) & 63;
        int ni    = (idx >> 9) & 3;
        int chunk = (idx >> 11) & 31;
        int colblk = idx >> 16;
        int col = colblk * 64 + ni * 16 + (lane & 15);
        int k   = chunk * 32 + (lane >> 4) * 8 + j;
        float v = (k < 768) ? W2[((size_t)(k >> 8) * 256 + (k & 255)) * 256 + col]
                            : root2[(size_t)(k - 768) * 256 + col];
        Wf[idx] = f2b(v);
    }
}

// ---------------- prep2: count_edges + comb_build
__global__ __launch_bounds__(256) void prep2(const int* __restrict__ ei,
                                             const int* __restrict__ et,
                                             int* __restrict__ cnt,
                                             const float* __restrict__ tab,
                                             const float* __restrict__ b1,
                                             bf16* __restrict__ comb) {
    int b = blockIdx.x, t = threadIdx.x;
    if (b < P2_CNT) {
        int e = b * 256 + t;
        if (e < NE) atomicAdd(&cnt[ei[NE + e] * NR + et[e]], 1);
        return;
    }
    b -= P2_CNT;
    {   // comb[r][cmb][d] = tab[r][s]+tab[r][8+c]+tab[r][16+p] (+b1 for r=3)
        int r = b >> 13, cmb = b & (NCMB - 1);
        int si = cmb >> 10, ci = (cmb >> 7) & 7, pi = cmb & 127;
        const float* tr = tab + (size_t)r * 144 * 256;
        float v = tr[si * 256 + t] + tr[(8 + ci) * 256 + t] + tr[(16 + pi) * 256 + t];
        if (r == 3) v += b1[t];
        comb[(size_t)b * 256 + t] = f2b(v);
    }
}

// ---------------- single-kernel counting-sort scan (validated r15): block base
// computed by coalesced sum of cnt[0 .. b*2048); last block writes off[NB].
__global__ __launch_bounds__(256) void scan_write(const int* __restrict__ cnt,
                                                  int* __restrict__ off,
                                                  int* __restrict__ cursor) {
    __shared__ int sred[256];
    __shared__ int wsum[4];
    int b = blockIdx.x, t = threadIdx.x;
    long lim = (long)b * CHUNK;
    int partial = 0;
    for (long i = t; i < lim; i += 256) partial += cnt[i];
    sred[t] = partial;
    __syncthreads();
    for (int st = 128; st; st >>= 1) { if (t < st) sred[t] += sred[t + st]; __syncthreads(); }
    int bbase = sred[0];

    int base = b * CHUNK + t * 8;
    int v[8], ts = 0;
#pragma unroll
    for (int j = 0; j < 8; ++j) { int i = base + j; v[j] = (i < NB) ? cnt[i] : 0; ts += v[j]; }
    int lane = t & 63, wv = t >> 6;
    int incl = ts;
    for (int d = 1; d < 64; d <<= 1) {
        int o = __shfl_up(incl, d, 64);
        if (lane >= d) incl += o;
    }
    if (lane == 63) wsum[wv] = incl;
    __syncthreads();
    int wbase = 0;
    for (int w = 0; w < wv; ++w) wbase += wsum[w];
    if (b == NBLK - 1 && t == 0)
        off[NB] = bbase + wsum[0] + wsum[1] + wsum[2] + wsum[3];   // == NE
    int run = bbase + wbase + incl - ts;
#pragma unroll
    for (int j = 0; j < 8; ++j) {
        int i = base + j;
        if (i < NB) { off[i] = run; cursor[i] = run; }
        run += v[j];
    }
}

// ---------------- bucket-sort edges: stores src AND combo[src]
__global__ __launch_bounds__(256) void scatter_edges(const int* __restrict__ ei,
                                                     const int* __restrict__ et,
                                                     const int* __restrict__ combo,
                                                     int* __restrict__ cursor,
                                                     int* __restrict__ eidx,
                                                     int* __restrict__ ecmb) {
    int e = blockIdx.x * 256 + threadIdx.x;
    if (e >= NE) return;
    int b = ei[NE + e] * NR + et[e];
    int pos = atomicAdd(&cursor[b], 1);
    int s = ei[e];
    eidx[pos] = s;
    ecmb[pos] = combo[s];
}

// ---------------- fused layer 1: 4 waves/block, 1 wave/dst, lane-split 8-deep gather
__global__ __launch_bounds__(256) void l1_fused(const int* __restrict__ off,
                                                const int* __restrict__ ecmb,
                                                const int* __restrict__ combo,
                                                const bf16* __restrict__ comb,
                                                bf16* __restrict__ h1) {
    int wave = threadIdx.x >> 6, lane = threadIdx.x & 63;
    int dst = blockIdx.x * 4 + wave;
    if (dst >= NN) return;
    int half = lane >> 5, li8 = (lane & 31) * 8;
    float acc[8];
    if (half == 0) {   // root slice (b1 pre-folded); only half0's acc is used
        int cmbD = combo[dst];
        short8 rv = *(const short8*)(comb + ((size_t)(3 * NCMB) + cmbD) * 256 + li8);
#pragma unroll
        for (int i = 0; i < 8; ++i) acc[i] = bs2f(rv[i]);
    } else {
#pragma unroll
        for (int i = 0; i < 8; ++i) acc[i] = 0.f;
    }
    for (int r = 0; r < NR; ++r) {
        int lo = off[dst * NR + r], hi = off[dst * NR + r + 1];
        if (hi <= lo) continue;                 // empty bucket contributes 0 (matches ref)
        const bf16* cr = comb + (size_t)r * NCMB * 256;
        float s[8] = {};
        int j = lo;
        for (; j + 8 <= hi; j += 8) {           // 4 rows/half in flight
            int c0 = ecmb[j + half],     c1 = ecmb[j + 2 + half];
            int c2 = ecmb[j + 4 + half], c3 = ecmb[j + 6 + half];
            short8 v0 = *(const short8*)(cr + (size_t)c0 * 256 + li8);
            short8 v1 = *(const short8*)(cr + (size_t)c1 * 256 + li8);
            short8 v2 = *(const short8*)(cr + (size_t)c2 * 256 + li8);
            short8 v3 = *(const short8*)(cr + (size_t)c3 * 256 + li8);
#pragma unroll
            for (int i = 0; i < 8; ++i)
                s[i] += (bs2f(v0[i]) + bs2f(v1[i])) + (bs2f(v2[i]) + bs2f(v3[i]));
        }
        for (; j + 2 <= hi; j += 2) {
            int c0 = ecmb[j + half];
            short8 v0 = *(const short8*)(cr + (size_t)c0 * 256 + li8);
#pragma unroll
            for (int i = 0; i < 8; ++i) s[i] += bs2f(v0[i]);
        }
        if (j < hi && half == 0) {              // odd remainder
            short8 v0 = *(const short8*)(cr + (size_t)ecmb[j] * 256 + li8);
#pragma unroll
            for (int i = 0; i < 8; ++i) s[i] += bs2f(v0[i]);
        }
        float inv = 1.0f / (float)(hi - lo);
#pragma unroll
        for (int i = 0; i < 8; ++i) {
            float tot = s[i] + __shfl_xor(s[i], 32);
            if (half == 0) acc[i] += tot * inv;
        }
    }
    if (half == 0) {
        short8 o;
#pragma unroll
        for (int i = 0; i < 8; ++i) o[i] = f2bs(fmaxf(acc[i], 0.f));
        *(short8*)(h1 + (size_t)dst * 256 + li8) = o;
    }
}

// ---------------- per-relation mean aggregation of h1:
// hagg[dst][r*256+d] = mean_{src in bucket(dst,r)} h1[src][d]   (0 if empty)
__global__ __launch_bounds__(256) void agg_all(const int* __restrict__ off,
                                               const int* __restrict__ eidx,
                                               const bf16* __restrict__ h1,
                                               bf16* __restrict__ hagg) {
    int wave = threadIdx.x >> 6, lane = threadIdx.x & 63;
    int dst = blockIdx.x * 4 + wave;
    if (dst >= NN) return;
    int half = lane >> 5, li8 = (lane & 31) * 8;
    for (int r = 0; r < NR; ++r) {
        int lo = off[dst * NR + r], hi = off[dst * NR + r + 1];
        float s[8] = {};
        int j = lo;
        for (; j + 8 <= hi; j += 8) {           // 4 rows/half in flight
            int e0 = eidx[j + half],     e1 = eidx[j + 2 + half];
            int e2 = eidx[j + 4 + half], e3 = eidx[j + 6 + half];
            short8 v0 = *(const short8*)(h1 + (size_t)e0 * 256 + li8);
            short8 v1 = *(const short8*)(h1 + (size_t)e1 * 256 + li8);
            short8 v2 = *(const short8*)(h1 + (size_t)e2 * 256 + li8);
            short8 v3 = *(const short8*)(h1 + (size_t)e3 * 256 + li8);
#pragma unroll
            for (int i = 0; i < 8; ++i)
                s[i] += (bs2f(v0[i]) + bs2f(v1[i])) + (bs2f(v2[i]) + bs2f(v3[i]));
        }
        for (; j + 2 <= hi; j += 2) {
            int e0 = eidx[j + half];
            short8 v0 = *(const short8*)(h1 + (size_t)e0 * 256 + li8);
#pragma unroll
            for (int i = 0; i < 8; ++i) s[i] += bs2f(v0[i]);
        }
        if (j < hi && half == 0) {
            short8 v0 = *(const short8*)(h1 + (size_t)eidx[j] * 256 + li8);
#pragma unroll
            for (int i = 0; i < 8; ++i) s[i] += bs2f(v0[i]);
        }
        float inv = (hi > lo) ? 1.0f / (float)(hi - lo) : 0.f;
        short8 o;
#pragma unroll
        for (int i = 0; i < 8; ++i) {
            float tot = s[i] + __shfl_xor(s[i], 32);
            o[i] = f2bs(tot * inv);
        }
        if (half == 0)
            *(short8*)(hagg + (size_t)dst * 768 + r * 256 + li8) = o;
    }
}

// ---------------- concat MFMA GEMM v8 = v7 (validated 66 us) + fused RLE pooling.
// Computes relu([hagg|h1] @ W2cat + b2) for a full 32-row x 256-col tile, stages
// it bf16 in the (reused) A-LDS, then per-graph RLE reduction -> pool atomics.
// h2 is never materialized in HBM. Wave-autonomous K-loop: no barrier until end.
__global__ __launch_bounds__(256) void gemm_cat(const bf16* __restrict__ hagg,
                                                const bf16* __restrict__ h1,
                                                const bf16* __restrict__ Wf,
                                                const float* __restrict__ bias,
                                                const int* __restrict__ batch,
                                                float* __restrict__ pool,
                                                float* __restrict__ gcnt) {
    __shared__ short lds[4][2][32 * 40];    // K-loop: per-wave A dbuf; epilogue: h2 tile
    const int t = threadIdx.x;
    const int wave = t >> 6, lane = t & 63;
    const int quad = lane >> 4, l16 = lane & 15;
    const int row0 = blockIdx.x * 32;
    const int colblk = wave;                // 0..3 -> 64-col group
    const int rsub = lane >> 2;        // 0..15: row within 16-row half
    const int ksub = (lane & 3) * 8;   // k-element offset within 32-chunk
    short* A0 = lds[wave][0];
    short* A1 = lds[wave][1];

    const int r0 = min(row0 + rsub, NN - 1);        // clamped (uses guarded)
    const int r1 = min(row0 + 16 + rsub, NN - 1);
    const bf16* gA0 = hagg + (size_t)r0 * 768 + ksub;
    const bf16* gA1 = hagg + (size_t)r1 * 768 + ksub;
    const bf16* gH0 = h1 + (size_t)r0 * 256 + ksub;
    const bf16* gH1 = h1 + (size_t)r1 * 256 + ksub;
    const short8* bbase = (const short8*)Wf + (size_t)colblk * 32 * 4 * 64 + lane;

    auto loadA2 = [&](int k0, short8& a0, short8& a1) {
        if (k0 < 768) { a0 = *(const short8*)(gA0 + k0); a1 = *(const short8*)(gA1 + k0); }
        else          { a0 = *(const short8*)(gH0 + k0 - 768); a1 = *(const short8*)(gH1 + k0 - 768); }
    };
    auto loadB = [&](int chunk, short8* bf4) {
        const short8* bp = bbase + (size_t)chunk * 4 * 64;
#pragma unroll
        for (int ni = 0; ni < 4; ++ni) bf4[ni] = bp[ni * 64];
    };

    floatx4 acc[2][4] = {};
    short8 aE0, aE1, bE[4];     // even-chunk register set
    short8 aO0, aO1, bO[4];     // odd-chunk register set
    loadA2(0, aE0, aE1);  loadB(0, bE);
    loadA2(32, aO0, aO1); loadB(1, bO);

#pragma unroll
    for (int i = 0; i < 32; i += 2) {
        // ---- even chunk i: parity buffer 0, set E
        *(short8*)&A0[rsub * 40 + ksub] = aE0;
        *(short8*)&A0[(16 + rsub) * 40 + ksub] = aE1;
        {
            short8 af0 = *(const short8*)&A0[l16 * 40 + quad * 8];
            short8 af1 = *(const short8*)&A0[(16 + l16) * 40 + quad * 8];
#pragma unroll
            for (int ni = 0; ni < 4; ++ni) {
                acc[0][ni] = __builtin_amdgcn_mfma_f32_16x16x32_bf16(af0, bE[ni], acc[0][ni], 0, 0, 0);
                acc[1][ni] = __builtin_amdgcn_mfma_f32_16x16x32_bf16(af1, bE[ni], acc[1][ni], 0, 0, 0);
            }
        }
        if (i + 2 < 32) { loadA2((i + 2) * 32, aE0, aE1); loadB(i + 2, bE); }
        // ---- odd chunk i+1: parity buffer 1, set O
        *(short8*)&A1[rsub * 40 + ksub] = aO0;
        *(short8*)&A1[(16 + rsub) * 40 + ksub] = aO1;
        {
            short8 af0 = *(const short8*)&A1[l16 * 40 + quad * 8];
            short8 af1 = *(const short8*)&A1[(16 + l16) * 40 + quad * 8];
#pragma unroll
            for (int ni = 0; ni < 4; ++ni) {
                acc[0][ni] = __builtin_amdgcn_mfma_f32_16x16x32_bf16(af0, bO[ni], acc[0][ni], 0, 0, 0);
                acc[1][ni] = __builtin_amdgcn_mfma_f32_16x16x32_bf16(af1, bO[ni], acc[1][ni], 0, 0, 0);
            }
        }
        if (i + 3 < 32) { loadA2((i + 3) * 32, aO0, aO1); loadB(i + 3, bO); }
    }

    // ---- epilogue: stage bf16 h2 tile into reused LDS (stride 260: quads land on
    // disjoint bank octets -> conflict-free), then RLE pooling (batch is SORTED).
    __syncthreads();                        // all waves done with A-LDS
    short* st = &lds[0][0][0];              // 32*260 = 8320 shorts <= 10240 avail
    // C/D layout: col = lane&15, row = quad*4 + reg   [m89/m91-verified]
#pragma unroll
    for (int mi = 0; mi < 2; ++mi) {
#pragma unroll
        for (int ni = 0; ni < 4; ++ni) {
            int n = colblk * 64 + ni * 16 + l16;
            float bn = bias[n];
#pragma unroll
            for (int ii = 0; ii < 4; ++ii) {
                int lrow = mi * 16 + quad * 4 + ii;
                float v = (row0 + lrow < NN) ? fmaxf(acc[mi][ni][ii] + bn, 0.f) : 0.f;
                st[lrow * 260 + n] = f2bs(v);
            }
        }
    }
    __syncthreads();
    int nrows = NN - row0; if (nrows > 32) nrows = 32;
    int curg = batch[row0];                 // wave-uniform broadcast
    float a = 0.f, cntf = 0.f;
    for (int rr = 0; rr < nrows; ++rr) {
        int g = batch[row0 + rr];
        if (g != curg) {
            atomicAdd(&pool[(size_t)curg * 256 + t], a);
            if (t == 0) atomicAdd(&gcnt[curg], cntf);
            a = 0.f; cntf = 0.f; curg = g;
        }
        a += bs2f(st[rr * 260 + t]);
        cntf += 1.f;
    }
    atomicAdd(&pool[(size_t)curg * 256 + t], a);
    if (t == 0) atomicAdd(&gcnt[curg], cntf);
}

// ---------------- head: out[g][c] = (pool[g]/cnt[g]) @ lin_w + lin_b  (f32 out)
__global__ __launch_bounds__(256) void final_head(const float* __restrict__ pool,
                                                  const float* __restrict__ gcnt,
                                                  const float* __restrict__ lin_w,
                                                  const float* __restrict__ lin_b,
                                                  float* __restrict__ out) {
    __shared__ float sm[256];
    int g = blockIdx.x, t = threadIdx.x;
    float inv = 1.0f / fmaxf(gcnt[g], 1.0f);
    sm[t] = pool[(size_t)g * 256 + t] * inv;
    __syncthreads();
    if (t < NCLS) {
        float s = lin_b[t];
        for (int d = 0; d < 256; ++d) s += sm[d] * lin_w[d * NCLS + t];
        out[g * NCLS + t] = s;
    }
}

extern "C" void kernel_launch(void* const* d_in, const int* in_sizes, int n_in,
                              void* d_out, int out_size, void* d_ws, size_t ws_size,
                              hipStream_t stream) {
    const int*   s_idx = (const int*)d_in[0];
    const int*   c_idx = (const int*)d_in[1];
    const int*   p_idx = (const int*)d_in[2];
    const int*   ei    = (const int*)d_in[3];   // (2, NE)
    const int*   et    = (const int*)d_in[4];
    const int*   batch = (const int*)d_in[5];
    const float* se    = (const float*)d_in[6];
    const float* ce    = (const float*)d_in[7];
    const float* pe    = (const float*)d_in[8];
    const float* W1    = (const float*)d_in[9];   // (3, 384, 256)
    const float* root1 = (const float*)d_in[10];  // (384, 256)
    const float* b1    = (const float*)d_in[11];
    const float* W2    = (const float*)d_in[12];  // (3, 256, 256)
    const float* root2 = (const float*)d_in[13];  // (256, 256)
    const float* b2    = (const float*)d_in[14];
    const float* lin_w = (const float*)d_in[15];
    const float* lin_b = (const float*)d_in[16];
    float* out = (float*)d_out;

    // ---- workspace carve-up (~148 MB; h2 eliminated)
    char* w = (char*)d_ws;
    size_t o = 0;
    auto alloc = [&](size_t bytes) -> void* {
        o = (o + 15) & ~(size_t)15;
        void* ptr = w + o;
        o += bytes;
        return ptr;
    };
    bf16*  hagg   = (bf16*) alloc((size_t)NN * 768 * 2);   // 76.8 MB
    bf16*  h1     = (bf16*) alloc((size_t)NN * 256 * 2);
    bf16*  comb   = (bf16*) alloc((size_t)4 * NCMB * 256 * 2);
    int*   combo  = (int*)  alloc((size_t)NN * 4);
    int*   eidx   = (int*)  alloc((size_t)NE * 4);
    int*   ecmb   = (int*)  alloc((size_t)NE * 4);
    int*   cnt    = (int*)  alloc((size_t)NB * 4);
    int*   off    = (int*)  alloc((size_t)(NB + 1) * 4);
    int*   cursor = (int*)  alloc((size_t)NB * 4);
    float* tab    = (float*)alloc((size_t)4 * 144 * 256 * 4);
    bf16*  Wf     = (bf16*) alloc((size_t)256 * 1024 * 2);
    float* pool   = (float*)alloc((size_t)NG * 256 * 4);   // pool + gcnt contiguous
    float* gcnt   = (float*)alloc((size_t)NG * 4);
    (void)ws_size;

    // ---- 1. all independent prep (combo ids, zeros, layer-1 tab GEMM, Wf shuffle)
    prep1<<<P1_TOTAL, 256, 0, stream>>>(s_idx, c_idx, p_idx, se, ce, pe,
                                        W1, root1, W2, root2,
                                        combo, (unsigned*)cnt, (unsigned*)pool, tab, Wf);
    // ---- 2. edge counts + combo-table build
    prep2<<<P2_TOTAL, 256, 0, stream>>>(ei, et, cnt, tab, b1, comb);
    // ---- 3. single-kernel CSR scan
    scan_write<<<NBLK, 256, 0, stream>>>(cnt, off, cursor);
    // ---- 4. bucket-sort edges
    scatter_edges<<<(NE + 255) / 256, 256, 0, stream>>>(ei, et, combo, cursor, eidx, ecmb);
    // ---- 5. layer 1: fully fused combo-table gather
    l1_fused<<<(NN + 3) / 4, 256, 0, stream>>>(off, ecmb, combo, comb, h1);
    // ---- 6. layer 2 aggregation (aggregate-before-transform)
    agg_all<<<(NN + 3) / 4, 256, 0, stream>>>(off, eidx, h1, hagg);
    // ---- 7. concat GEMM + fused bias/relu + fused RLE pooling (h2 never hits HBM)
    gemm_cat<<<(NN + 31) / 32, 256, 0, stream>>>(hagg, h1, Wf, b2, batch, pool, gcnt);
    // ---- 8. head
    final_head<<<NG, 256, 0, stream>>>(pool, gcnt, lin_w, lin_b, out);
}

// Round 17
// 392.370 us; speedup vs baseline: 1.2800x; 1.1678x over previous
//
#include <hip/hip_runtime.h>
#include <hip/hip_bf16.h>

#define NN 50000          // nodes
#define NE 800000         // edges
#define NR 3              // relations
#define NG 500            // graphs
#define NB (NN * NR)      // (dst, rel) buckets = 150000
#define NCLS 10
#define NCMB 8192         // 8 shapes * 8 colors * 128 positions
#define CHUNK 2048        // scan elements per block
#define NBLK ((NB + CHUNK - 1) / CHUNK)   // 74

// prep1 role block ranges
#define P1_COMBO   196                        // node_combo: 50000/256
#define P1_ZCNT    586                        // zero cnt: 150000/256
#define P1_ZPOOL   502                        // zero pool+gcnt: 128500/256
#define P1_TAB     576                        // tab_gemm: 4*144
#define P1_WF      1024                       // conv_w2cat: 256*1024/256
#define P1_TOTAL   (P1_COMBO + P1_ZCNT + P1_ZPOOL + P1_TAB + P1_WF)   // 2884
// prep2 role block ranges
#define P2_CNT     3125                       // count_edges: NE/256
#define P2_COMB    (4 * NCMB)                 // comb_build
#define P2_TOTAL   (P2_CNT + P2_COMB)         // 35893

typedef __hip_bfloat16 bf16;
typedef __attribute__((ext_vector_type(8))) short short8;   // bf16x8 MFMA frag
typedef __attribute__((ext_vector_type(4))) float floatx4;  // MFMA accumulator

static __device__ __forceinline__ float b2f(bf16 x) { return __bfloat162float(x); }
static __device__ __forceinline__ bf16  f2b(float x) { return __float2bfloat16(x); }
static __device__ __forceinline__ float bs2f(short x) {
    return __bfloat162float(*reinterpret_cast<const bf16*>(&x));
}
static __device__ __forceinline__ short f2bs(float x) {
    bf16 b = __float2bfloat16(x);
    return *reinterpret_cast<const short*>(&b);
}

// ---------------- prep1: all independent prep work, role-dispatched by blockIdx
__global__ __launch_bounds__(256) void prep1(const int* __restrict__ s,
                                             const int* __restrict__ c,
                                             const int* __restrict__ p,
                                             const float* __restrict__ se,
                                             const float* __restrict__ ce,
                                             const float* __restrict__ pe,
                                             const float* __restrict__ W1,
                                             const float* __restrict__ root1,
                                             const float* __restrict__ W2,
                                             const float* __restrict__ root2,
                                             int* __restrict__ combo,
                                             unsigned* __restrict__ cnt,
                                             unsigned* __restrict__ poolz,
                                             float* __restrict__ tab,
                                             bf16* __restrict__ Wf) {
    int b = blockIdx.x, t = threadIdx.x;
    if (b < P1_COMBO) {
        int n = b * 256 + t;
        if (n < NN) combo[n] = (s[n] << 10) | (c[n] << 7) | p[n];
        return;
    }
    b -= P1_COMBO;
    if (b < P1_ZCNT) {
        int i = b * 256 + t;
        if (i < NB) cnt[i] = 0u;
        return;
    }
    b -= P1_ZCNT;
    if (b < P1_ZPOOL) {
        int i = b * 256 + t;
        if (i < NG * 256 + NG) poolz[i] = 0u;
        return;
    }
    b -= P1_ZPOOL;
    if (b < P1_TAB) {
        // tab[r][row][n]: rows 0..7 = se@Wseg0, 8..15 = ce@Wseg1, 16..143 = pe@Wseg2
        int r = b / 144, row = b % 144;
        const float* A; int segk;
        if (row < 8)       { A = se + row * 128;        segk = 0; }
        else if (row < 16) { A = ce + (row - 8) * 128;  segk = 128; }
        else               { A = pe + (row - 16) * 128; segk = 256; }
        const float* W = (r < 3) ? (W1 + (size_t)r * 384 * 256) : root1;
        float acc = 0.f;
        for (int k = 0; k < 128; ++k)
            acc += A[k] * W[(size_t)(segk + k) * 256 + t];
        tab[((size_t)r * 144 + row) * 256 + t] = acc;
        return;
    }
    b -= P1_TAB;
    {   // conv_w2cat: Wf in MFMA-fragment order (wave B-frag = contiguous 1 KB)
        int idx = b * 256 + t;
        int j     = idx & 7;
        int lane  = (idx >> 3) & 63;
        int ni    = (idx >> 9) & 3;
        int chunk = (idx >> 11) & 31;
        int colblk = idx >> 16;
        int col = colblk * 64 + ni * 16 + (lane & 15);
        int k   = chunk * 32 + (lane >> 4) * 8 + j;
        float v = (k < 768) ? W2[((size_t)(k >> 8) * 256 + (k & 255)) * 256 + col]
                            : root2[(size_t)(k - 768) * 256 + col];
        Wf[idx] = f2b(v);
    }
}

// ---------------- prep2: count_edges + comb_build
__global__ __launch_bounds__(256) void prep2(const int* __restrict__ ei,
                                             const int* __restrict__ et,
                                             int* __restrict__ cnt,
                                             const float* __restrict__ tab,
                                             const float* __restrict__ b1,
                                             bf16* __restrict__ comb) {
    int b = blockIdx.x, t = threadIdx.x;
    if (b < P2_CNT) {
        int e = b * 256 + t;
        if (e < NE) atomicAdd(&cnt[ei[NE + e] * NR + et[e]], 1);
        return;
    }
    b -= P2_CNT;
    {   // comb[r][cmb][d] = tab[r][s]+tab[r][8+c]+tab[r][16+p] (+b1 for r=3)
        int r = b >> 13, cmb = b & (NCMB - 1);
        int si = cmb >> 10, ci = (cmb >> 7) & 7, pi = cmb & 127;
        const float* tr = tab + (size_t)r * 144 * 256;
        float v = tr[si * 256 + t] + tr[(8 + ci) * 256 + t] + tr[(16 + pi) * 256 + t];
        if (r == 3) v += b1[t];
        comb[(size_t)b * 256 + t] = f2b(v);
    }
}

// ---------------- counting-sort scan, phase A: per-block (2048-elem) totals
// (validated r12/r13 — parallel 8-elem/thread reduction, ~3 us)
__global__ __launch_bounds__(256) void scan_block_sums(const int* __restrict__ cnt,
                                                       int* __restrict__ bsum) {
    __shared__ int sm[256];
    int b = blockIdx.x, t = threadIdx.x;
    int base = b * CHUNK + t * 8, s = 0;
#pragma unroll
    for (int j = 0; j < 8; ++j) { int i = base + j; if (i < NB) s += cnt[i]; }
    sm[t] = s; __syncthreads();
    for (int st = 128; st; st >>= 1) { if (t < st) sm[t] += sm[t + st]; __syncthreads(); }
    if (!t) bsum[b] = sm[0];
}

// ---------------- phase B+C merged: 74-elem wave-uniform prefix over bsum + in-block scan
// (validated r12/r13 — never appeared in top-5)
__global__ __launch_bounds__(256) void scan_write(const int* __restrict__ cnt,
                                                  const int* __restrict__ bsum,
                                                  int* __restrict__ off,
                                                  int* __restrict__ cursor) {
    int b = blockIdx.x, t = threadIdx.x;
    int bbase = 0;                              // wave-uniform 74-iteration prefix
    for (int i = 0; i < b; ++i) bbase += bsum[i];
    if (b == 0 && t == 0) {
        int tot = 0;
        for (int i = 0; i < NBLK; ++i) tot += bsum[i];
        off[NB] = tot;                          // == NE
    }
    int base = b * CHUNK + t * 8;
    int v[8], ts = 0;
#pragma unroll
    for (int j = 0; j < 8; ++j) { int i = base + j; v[j] = (i < NB) ? cnt[i] : 0; ts += v[j]; }
    int lane = t & 63, wv = t >> 6;
    int incl = ts;
    for (int d = 1; d < 64; d <<= 1) {
        int o = __shfl_up(incl, d, 64);
        if (lane >= d) incl += o;
    }
    __shared__ int wsum[4];
    if (lane == 63) wsum[wv] = incl;
    __syncthreads();
    int wbase = 0;
    for (int w = 0; w < wv; ++w) wbase += wsum[w];
    int run = bbase + wbase + incl - ts;
#pragma unroll
    for (int j = 0; j < 8; ++j) {
        int i = base + j;
        if (i < NB) { off[i] = run; cursor[i] = run; }
        run += v[j];
    }
}

// ---------------- bucket-sort edges: stores src AND combo[src]
__global__ __launch_bounds__(256) void scatter_edges(const int* __restrict__ ei,
                                                     const int* __restrict__ et,
                                                     const int* __restrict__ combo,
                                                     int* __restrict__ cursor,
                                                     int* __restrict__ eidx,
                                                     int* __restrict__ ecmb) {
    int e = blockIdx.x * 256 + threadIdx.x;
    if (e >= NE) return;
    int b = ei[NE + e] * NR + et[e];
    int pos = atomicAdd(&cursor[b], 1);
    int s = ei[e];
    eidx[pos] = s;
    ecmb[pos] = combo[s];
}

// ---------------- fused layer 1: 4 waves/block, 1 wave/dst, lane-split 8-deep gather
__global__ __launch_bounds__(256) void l1_fused(const int* __restrict__ off,
                                                const int* __restrict__ ecmb,
                                                const int* __restrict__ combo,
                                                const bf16* __restrict__ comb,
                                                bf16* __restrict__ h1) {
    int wave = threadIdx.x >> 6, lane = threadIdx.x & 63;
    int dst = blockIdx.x * 4 + wave;
    if (dst >= NN) return;
    int half = lane >> 5, li8 = (lane & 31) * 8;
    float acc[8];
    if (half == 0) {   // root slice (b1 pre-folded); only half0's acc is used
        int cmbD = combo[dst];
        short8 rv = *(const short8*)(comb + ((size_t)(3 * NCMB) + cmbD) * 256 + li8);
#pragma unroll
        for (int i = 0; i < 8; ++i) acc[i] = bs2f(rv[i]);
    } else {
#pragma unroll
        for (int i = 0; i < 8; ++i) acc[i] = 0.f;
    }
    for (int r = 0; r < NR; ++r) {
        int lo = off[dst * NR + r], hi = off[dst * NR + r + 1];
        if (hi <= lo) continue;                 // empty bucket contributes 0 (matches ref)
        const bf16* cr = comb + (size_t)r * NCMB * 256;
        float s[8] = {};
        int j = lo;
        for (; j + 8 <= hi; j += 8) {           // 4 rows/half in flight
            int c0 = ecmb[j + half],     c1 = ecmb[j + 2 + half];
            int c2 = ecmb[j + 4 + half], c3 = ecmb[j + 6 + half];
            short8 v0 = *(const short8*)(cr + (size_t)c0 * 256 + li8);
            short8 v1 = *(const short8*)(cr + (size_t)c1 * 256 + li8);
            short8 v2 = *(const short8*)(cr + (size_t)c2 * 256 + li8);
            short8 v3 = *(const short8*)(cr + (size_t)c3 * 256 + li8);
#pragma unroll
            for (int i = 0; i < 8; ++i)
                s[i] += (bs2f(v0[i]) + bs2f(v1[i])) + (bs2f(v2[i]) + bs2f(v3[i]));
        }
        for (; j + 2 <= hi; j += 2) {
            int c0 = ecmb[j + half];
            short8 v0 = *(const short8*)(cr + (size_t)c0 * 256 + li8);
#pragma unroll
            for (int i = 0; i < 8; ++i) s[i] += bs2f(v0[i]);
        }
        if (j < hi && half == 0) {              // odd remainder
            short8 v0 = *(const short8*)(cr + (size_t)ecmb[j] * 256 + li8);
#pragma unroll
            for (int i = 0; i < 8; ++i) s[i] += bs2f(v0[i]);
        }
        float inv = 1.0f / (float)(hi - lo);
#pragma unroll
        for (int i = 0; i < 8; ++i) {
            float tot = s[i] + __shfl_xor(s[i], 32);
            if (half == 0) acc[i] += tot * inv;
        }
    }
    if (half == 0) {
        short8 o;
#pragma unroll
        for (int i = 0; i < 8; ++i) o[i] = f2bs(fmaxf(acc[i], 0.f));
        *(short8*)(h1 + (size_t)dst * 256 + li8) = o;
    }
}

// ---------------- per-relation mean aggregation of h1:
// hagg[dst][r*256+d] = mean_{src in bucket(dst,r)} h1[src][d]   (0 if empty)
__global__ __launch_bounds__(256) void agg_all(const int* __restrict__ off,
                                               const int* __restrict__ eidx,
                                               const bf16* __restrict__ h1,
                                               bf16* __restrict__ hagg) {
    int wave = threadIdx.x >> 6, lane = threadIdx.x & 63;
    int dst = blockIdx.x * 4 + wave;
    if (dst >= NN) return;
    int half = lane >> 5, li8 = (lane & 31) * 8;
    for (int r = 0; r < NR; ++r) {
        int lo = off[dst * NR + r], hi = off[dst * NR + r + 1];
        float s[8] = {};
        int j = lo;
        for (; j + 8 <= hi; j += 8) {           // 4 rows/half in flight
            int e0 = eidx[j + half],     e1 = eidx[j + 2 + half];
            int e2 = eidx[j + 4 + half], e3 = eidx[j + 6 + half];
            short8 v0 = *(const short8*)(h1 + (size_t)e0 * 256 + li8);
            short8 v1 = *(const short8*)(h1 + (size_t)e1 * 256 + li8);
            short8 v2 = *(const short8*)(h1 + (size_t)e2 * 256 + li8);
            short8 v3 = *(const short8*)(h1 + (size_t)e3 * 256 + li8);
#pragma unroll
            for (int i = 0; i < 8; ++i)
                s[i] += (bs2f(v0[i]) + bs2f(v1[i])) + (bs2f(v2[i]) + bs2f(v3[i]));
        }
        for (; j + 2 <= hi; j += 2) {
            int e0 = eidx[j + half];
            short8 v0 = *(const short8*)(h1 + (size_t)e0 * 256 + li8);
#pragma unroll
            for (int i = 0; i < 8; ++i) s[i] += bs2f(v0[i]);
        }
        if (j < hi && half == 0) {
            short8 v0 = *(const short8*)(h1 + (size_t)eidx[j] * 256 + li8);
#pragma unroll
            for (int i = 0; i < 8; ++i) s[i] += bs2f(v0[i]);
        }
        float inv = (hi > lo) ? 1.0f / (float)(hi - lo) : 0.f;
        short8 o;
#pragma unroll
        for (int i = 0; i < 8; ++i) {
            float tot = s[i] + __shfl_xor(s[i], 32);
            o[i] = f2bs(tot * inv);
        }
        if (half == 0)
            *(short8*)(hagg + (size_t)dst * 768 + r * 256 + li8) = o;
    }
}

// ---------------- concat MFMA GEMM v8 (validated r16): v7 wave-autonomous K-loop
// + fused bias/relu + fused RLE pooling. h2 never hits HBM.
__global__ __launch_bounds__(256) void gemm_cat(const bf16* __restrict__ hagg,
                                                const bf16* __restrict__ h1,
                                                const bf16* __restrict__ Wf,
                                                const float* __restrict__ bias,
                                                const int* __restrict__ batch,
                                                float* __restrict__ pool,
                                                float* __restrict__ gcnt) {
    __shared__ short lds[4][2][32 * 40];    // K-loop: per-wave A dbuf; epilogue: h2 tile
    const int t = threadIdx.x;
    const int wave = t >> 6, lane = t & 63;
    const int quad = lane >> 4, l16 = lane & 15;
    const int row0 = blockIdx.x * 32;
    const int colblk = wave;                // 0..3 -> 64-col group
    const int rsub = lane >> 2;        // 0..15: row within 16-row half
    const int ksub = (lane & 3) * 8;   // k-element offset within 32-chunk
    short* A0 = lds[wave][0];
    short* A1 = lds[wave][1];

    const int r0 = min(row0 + rsub, NN - 1);        // clamped (uses guarded)
    const int r1 = min(row0 + 16 + rsub, NN - 1);
    const bf16* gA0 = hagg + (size_t)r0 * 768 + ksub;
    const bf16* gA1 = hagg + (size_t)r1 * 768 + ksub;
    const bf16* gH0 = h1 + (size_t)r0 * 256 + ksub;
    const bf16* gH1 = h1 + (size_t)r1 * 256 + ksub;
    const short8* bbase = (const short8*)Wf + (size_t)colblk * 32 * 4 * 64 + lane;

    auto loadA2 = [&](int k0, short8& a0, short8& a1) {
        if (k0 < 768) { a0 = *(const short8*)(gA0 + k0); a1 = *(const short8*)(gA1 + k0); }
        else          { a0 = *(const short8*)(gH0 + k0 - 768); a1 = *(const short8*)(gH1 + k0 - 768); }
    };
    auto loadB = [&](int chunk, short8* bf4) {
        const short8* bp = bbase + (size_t)chunk * 4 * 64;
#pragma unroll
        for (int ni = 0; ni < 4; ++ni) bf4[ni] = bp[ni * 64];
    };

    floatx4 acc[2][4] = {};
    short8 aE0, aE1, bE[4];     // even-chunk register set
    short8 aO0, aO1, bO[4];     // odd-chunk register set
    loadA2(0, aE0, aE1);  loadB(0, bE);
    loadA2(32, aO0, aO1); loadB(1, bO);

#pragma unroll
    for (int i = 0; i < 32; i += 2) {
        // ---- even chunk i: parity buffer 0, set E
        *(short8*)&A0[rsub * 40 + ksub] = aE0;
        *(short8*)&A0[(16 + rsub) * 40 + ksub] = aE1;
        {
            short8 af0 = *(const short8*)&A0[l16 * 40 + quad * 8];
            short8 af1 = *(const short8*)&A0[(16 + l16) * 40 + quad * 8];
#pragma unroll
            for (int ni = 0; ni < 4; ++ni) {
                acc[0][ni] = __builtin_amdgcn_mfma_f32_16x16x32_bf16(af0, bE[ni], acc[0][ni], 0, 0, 0);
                acc[1][ni] = __builtin_amdgcn_mfma_f32_16x16x32_bf16(af1, bE[ni], acc[1][ni], 0, 0, 0);
            }
        }
        if (i + 2 < 32) { loadA2((i + 2) * 32, aE0, aE1); loadB(i + 2, bE); }
        // ---- odd chunk i+1: parity buffer 1, set O
        *(short8*)&A1[rsub * 40 + ksub] = aO0;
        *(short8*)&A1[(16 + rsub) * 40 + ksub] = aO1;
        {
            short8 af0 = *(const short8*)&A1[l16 * 40 + quad * 8];
            short8 af1 = *(const short8*)&A1[(16 + l16) * 40 + quad * 8];
#pragma unroll
            for (int ni = 0; ni < 4; ++ni) {
                acc[0][ni] = __builtin_amdgcn_mfma_f32_16x16x32_bf16(af0, bO[ni], acc[0][ni], 0, 0, 0);
                acc[1][ni] = __builtin_amdgcn_mfma_f32_16x16x32_bf16(af1, bO[ni], acc[1][ni], 0, 0, 0);
            }
        }
        if (i + 3 < 32) { loadA2((i + 3) * 32, aO0, aO1); loadB(i + 3, bO); }
    }

    // ---- epilogue: stage bf16 h2 tile into reused LDS (stride 260), then RLE pooling
    __syncthreads();                        // all waves done with A-LDS
    short* st = &lds[0][0][0];              // 32*260 = 8320 shorts <= 10240 avail
    // C/D layout: col = lane&15, row = quad*4 + reg   [m89/m91-verified]
#pragma unroll
    for (int mi = 0; mi < 2; ++mi) {
#pragma unroll
        for (int ni = 0; ni < 4; ++ni) {
            int n = colblk * 64 + ni * 16 + l16;
            float bn = bias[n];
#pragma unroll
            for (int ii = 0; ii < 4; ++ii) {
                int lrow = mi * 16 + quad * 4 + ii;
                float v = (row0 + lrow < NN) ? fmaxf(acc[mi][ni][ii] + bn, 0.f) : 0.f;
                st[lrow * 260 + n] = f2bs(v);
            }
        }
    }
    __syncthreads();
    int nrows = NN - row0; if (nrows > 32) nrows = 32;
    int curg = batch[row0];                 // wave-uniform broadcast
    float a = 0.f, cntf = 0.f;
    for (int rr = 0; rr < nrows; ++rr) {
        int g = batch[row0 + rr];
        if (g != curg) {
            atomicAdd(&pool[(size_t)curg * 256 + t], a);
            if (t == 0) atomicAdd(&gcnt[curg], cntf);
            a = 0.f; cntf = 0.f; curg = g;
        }
        a += bs2f(st[rr * 260 + t]);
        cntf += 1.f;
    }
    atomicAdd(&pool[(size_t)curg * 256 + t], a);
    if (t == 0) atomicAdd(&gcnt[curg], cntf);
}

// ---------------- head: out[g][c] = (pool[g]/cnt[g]) @ lin_w + lin_b  (f32 out)
__global__ __launch_bounds__(256) void final_head(const float* __restrict__ pool,
                                                  const float* __restrict__ gcnt,
                                                  const float* __restrict__ lin_w,
                                                  const float* __restrict__ lin_b,
                                                  float* __restrict__ out) {
    __shared__ float sm[256];
    int g = blockIdx.x, t = threadIdx.x;
    float inv = 1.0f / fmaxf(gcnt[g], 1.0f);
    sm[t] = pool[(size_t)g * 256 + t] * inv;
    __syncthreads();
    if (t < NCLS) {
        float s = lin_b[t];
        for (int d = 0; d < 256; ++d) s += sm[d] * lin_w[d * NCLS + t];
        out[g * NCLS + t] = s;
    }
}

extern "C" void kernel_launch(void* const* d_in, const int* in_sizes, int n_in,
                              void* d_out, int out_size, void* d_ws, size_t ws_size,
                              hipStream_t stream) {
    const int*   s_idx = (const int*)d_in[0];
    const int*   c_idx = (const int*)d_in[1];
    const int*   p_idx = (const int*)d_in[2];
    const int*   ei    = (const int*)d_in[3];   // (2, NE)
    const int*   et    = (const int*)d_in[4];
    const int*   batch = (const int*)d_in[5];
    const float* se    = (const float*)d_in[6];
    const float* ce    = (const float*)d_in[7];
    const float* pe    = (const float*)d_in[8];
    const float* W1    = (const float*)d_in[9];   // (3, 384, 256)
    const float* root1 = (const float*)d_in[10];  // (384, 256)
    const float* b1    = (const float*)d_in[11];
    const float* W2    = (const float*)d_in[12];  // (3, 256, 256)
    const float* root2 = (const float*)d_in[13];  // (256, 256)
    const float* b2    = (const float*)d_in[14];
    const float* lin_w = (const float*)d_in[15];
    const float* lin_b = (const float*)d_in[16];
    float* out = (float*)d_out;

    // ---- workspace carve-up (~148 MB; h2 eliminated)
    char* w = (char*)d_ws;
    size_t o = 0;
    auto alloc = [&](size_t bytes) -> void* {
        o = (o + 15) & ~(size_t)15;
        void* ptr = w + o;
        o += bytes;
        return ptr;
    };
    bf16*  hagg   = (bf16*) alloc((size_t)NN * 768 * 2);   // 76.8 MB
    bf16*  h1     = (bf16*) alloc((size_t)NN * 256 * 2);
    bf16*  comb   = (bf16*) alloc((size_t)4 * NCMB * 256 * 2);
    int*   combo  = (int*)  alloc((size_t)NN * 4);
    int*   eidx   = (int*)  alloc((size_t)NE * 4);
    int*   ecmb   = (int*)  alloc((size_t)NE * 4);
    int*   cnt    = (int*)  alloc((size_t)NB * 4);
    int*   off    = (int*)  alloc((size_t)(NB + 1) * 4);
    int*   cursor = (int*)  alloc((size_t)NB * 4);
    int*   bsum   = (int*)  alloc((size_t)NBLK * 4);
    float* tab    = (float*)alloc((size_t)4 * 144 * 256 * 4);
    bf16*  Wf     = (bf16*) alloc((size_t)256 * 1024 * 2);
    float* pool   = (float*)alloc((size_t)NG * 256 * 4);   // pool + gcnt contiguous
    float* gcnt  = (float*)alloc((size_t)NG * 4);
    (void)ws_size;

    // ---- 1. all independent prep (combo ids, zeros, layer-1 tab GEMM, Wf shuffle)
    prep1<<<P1_TOTAL, 256, 0, stream>>>(s_idx, c_idx, p_idx, se, ce, pe,
                                        W1, root1, W2, root2,
                                        combo, (unsigned*)cnt, (unsigned*)pool, tab, Wf);
    // ---- 2. edge counts + combo-table build
    prep2<<<P2_TOTAL, 256, 0, stream>>>(ei, et, cnt, tab, b1, comb);
    // ---- 3-4. CSR scan (two-kernel form: parallel block sums + cheap bsum prefix)
    scan_block_sums<<<NBLK, 256, 0, stream>>>(cnt, bsum);
    scan_write<<<NBLK, 256, 0, stream>>>(cnt, bsum, off, cursor);
    // ---- 5. bucket-sort edges
    scatter_edges<<<(NE + 255) / 256, 256, 0, stream>>>(ei, et, combo, cursor, eidx, ecmb);
    // ---- 6. layer 1: fully fused combo-table gather
    l1_fused<<<(NN + 3) / 4, 256, 0, stream>>>(off, ecmb, combo, comb, h1);
    // ---- 7. layer 2 aggregation (aggregate-before-transform)
    agg_all<<<(NN + 3) / 4, 256, 0, stream>>>(off, eidx, h1, hagg);
    // ---- 8. concat GEMM + fused bias/relu + fused RLE pooling (h2 never hits HBM)
    gemm_cat<<<(NN + 31) / 32, 256, 0, stream>>>(hagg, h1, Wf, b2, batch, pool, gcnt);
    // ---- 9. head
    final_head<<<NG, 256, 0, stream>>>(pool, gcnt, lin_w, lin_b, out);
}